// Round 10
// baseline (235.395 us; speedup 1.0000x reference)
//
#include <hip/hip_runtime.h>
#include <cstdint>
#include <cstddef>

#define B_ 4
#define T_ 2048
#define C_ 1024
#define M_ (B_ * T_)   // 8192 rows
#define QK_STRIDE 2048
#define NT 32          // K-tiles of BK=32 (gemm_s)

typedef unsigned short u16;
typedef _Float16 half8 __attribute__((ext_vector_type(8)));
typedef float f32x16 __attribute__((ext_vector_type(16)));
typedef unsigned short ushort8v __attribute__((ext_vector_type(8)));

__device__ __forceinline__ ushort4 cvt4(float4 v) {
    ushort4 o;
    _Float16 a = (_Float16)v.x; o.x = __builtin_bit_cast(unsigned short, a);
    _Float16 b = (_Float16)v.y; o.y = __builtin_bit_cast(unsigned short, b);
    _Float16 c = (_Float16)v.z; o.z = __builtin_bit_cast(unsigned short, c);
    _Float16 d = (_Float16)v.w; o.w = __builtin_bit_cast(unsigned short, d);
    return o;
}

// ================= layouts =================
// frag chunk (mt, ks) = 1KB at ((mt*64+ks)*512) u16; lane l holds
// Mat[row=mt*32+(l&31)][k=ks*16+(l>>5)*8+e].
// V-frag (PV B-operand): element [tok][ch] at
//   ((tok>>4)*32 + (ch>>5))*512 + ((ch&31) + 32*((tok>>3)&1))*8 + (tok&7)
// qkh: row-major [M][2048] = Q(0..1023) | K(1024..2047) per row.

// ---------------- prologue: coalesced LDS-transpose to frag-major --------
__global__ void prologue2(const float* __restrict__ x,
                          const float* __restrict__ Wq, const float* __restrict__ Wk,
                          const float* __restrict__ Wv, const float* __restrict__ Wo,
                          const float* __restrict__ bq, const float* __restrict__ bk,
                          const float* __restrict__ bv,
                          u16* __restrict__ xf, u16* __restrict__ wfq,
                          u16* __restrict__ wfo, float* __restrict__ bcat) {
    const int blk = blockIdx.x;
    const int tid = threadIdx.x;
    if (blk >= 3072) {
        int i = (blk - 3072) * 256 + tid;
        const float* src = (i < 1024) ? bq : (i < 2048) ? bk : bv;
        bcat[i] = src[i & 1023];
        return;
    }
    __shared__ ushort8v g16[512];   // 32 rows x 16 granules, XOR-swizzled
    const float* src;
    u16* dst;
    size_t chunk_base;
    int kg;
    if (blk < 2048) {
        const int mt = blk >> 3; kg = blk & 7;
        src = x + (size_t)mt * 32 * C_;
        dst = xf; chunk_base = (size_t)mt * 64;
    } else {
        const int w = blk - 2048;
        const int mat = w >> 8, nt = (w >> 3) & 31; kg = w & 7;
        src = ((mat == 0) ? Wq : (mat == 1) ? Wk : (mat == 2) ? Wv : Wo)
              + (size_t)nt * 32 * C_;
        if (mat < 3) { dst = wfq; chunk_base = (size_t)(mat * 32 + nt) * 64; }
        else         { dst = wfo; chunk_base = (size_t)nt * 64; }
    }
    const int r = tid >> 3, gc = (tid & 7) * 2;
    const float4* s4 = (const float4*)(src + (size_t)r * C_ + kg * 128 + (tid & 7) * 16);
    float4 f0 = s4[0], f1 = s4[1], f2 = s4[2], f3 = s4[3];
    ushort4 h0 = cvt4(f0), h1 = cvt4(f1), h2 = cvt4(f2), h3 = cvt4(f3);
    ushort8v ga, gb;
    ga[0]=h0.x; ga[1]=h0.y; ga[2]=h0.z; ga[3]=h0.w;
    ga[4]=h1.x; ga[5]=h1.y; ga[6]=h1.z; ga[7]=h1.w;
    gb[0]=h2.x; gb[1]=h2.y; gb[2]=h2.z; gb[3]=h2.w;
    gb[4]=h3.x; gb[5]=h3.y; gb[6]=h3.z; gb[7]=h3.w;
    g16[r * 16 + ((gc    ) ^ (r & 15))] = ga;
    g16[r * 16 + ((gc + 1) ^ (r & 15))] = gb;
    __syncthreads();
    const int lane = tid & 63, rr = lane & 31, hi = lane >> 5;
#pragma unroll
    for (int r2 = 0; r2 < 2; ++r2) {
        const int ksl = r2 * 4 + (tid >> 6);
        const int g = ksl * 2 + hi;
        ushort8v v = g16[rr * 16 + (g ^ (rr & 15))];
        *(ushort8v*)(dst + ((chunk_base + kg * 8 + ksl) * 64 + lane) * 8) = v;
    }
}

#define AS1_ __attribute__((address_space(1)))
#define AS3_ __attribute__((address_space(3)))

__device__ __forceinline__ void gload16(const u16* g, u16* l) {
    __builtin_amdgcn_global_load_lds((AS1_ void*)g, (AS3_ void*)l, 16, 0, 0);
}

#define MFMA_ __builtin_amdgcn_mfma_f32_32x32x16_f16
#define LD8_(p) (*(const half8*)(p))
#define BAR_  asm volatile("s_barrier" ::: "memory")
#define WL0_  asm volatile("s_waitcnt lgkmcnt(0)" ::: "memory")

// ================= gemm8b: m201-faithful 8-phase QKV GEMM =================
// BM=256 x BN=256 x BK=64; 512 thr, 8 waves (2M x 4N), wave 128x64, acc 4x2.
// K split into 32 HALVES (32 k of depth each = 2 k-steps). 4 half-buffers x
// 32KB = 128KB LDS, cycling H&3. While computing half H, stage half H+3
// (4 gloads/thread over 2 phases) into buffer (H+3)&3 (= (H-1)&3, whose
// reads finished before H-1's final barrier -> WAR-safe).
// Phase = {6 ds_read_b128 ; 2 gload ; s_barrier ; lgkmcnt(0) ; setprio(1)
// 8 MFMA setprio(0) ; s_barrier}. vmcnt ONLY at half end: outstanding at
// that point = halves H+2,H+3 = 8 loads -> vmcnt(8) certifies H+1. Tail:
// 8 (H=28), 4 (H=29), 0 (H=30), none (H=31). NEVER drains mid-loop.

#define WV8_  asm volatile("s_waitcnt vmcnt(8)" ::: "memory")
#define WV4_  asm volatile("s_waitcnt vmcnt(4)" ::: "memory")
#define WV0_  asm volatile("s_waitcnt vmcnt(0)" ::: "memory")

// stage chunk (row rbase+RR, k-step kgs+S) of this wave's matrix
#define STG8(SB, HH, RR, S)                                                 \
    gload16(gw##RR + (size_t)(((HH) + 3) * 2 + (S)) * 512,                  \
            (SB) + ldst##RR##S)

#define PHASE8(CB, SB, HH, KSL, DOSTG, RR)                                  \
  { half8 a0 = LD8_((CB) + ((4*wm+0)*2 + (KSL))*512 + la8);                 \
    half8 a1 = LD8_((CB) + ((4*wm+1)*2 + (KSL))*512 + la8);                 \
    half8 a2 = LD8_((CB) + ((4*wm+2)*2 + (KSL))*512 + la8);                 \
    half8 a3 = LD8_((CB) + ((4*wm+3)*2 + (KSL))*512 + la8);                 \
    half8 bv0 = LD8_((CB) + 8192 + ((2*wn+0)*2 + (KSL))*512 + la8);         \
    half8 bv1 = LD8_((CB) + 8192 + ((2*wn+1)*2 + (KSL))*512 + la8);         \
    if (DOSTG) { STG8(SB, HH, RR, 0); STG8(SB, HH, RR, 1); }                \
    BAR_; WL0_;                                                             \
    __builtin_amdgcn_s_setprio(1);                                          \
    acc00 = MFMA_(a0, bv0, acc00, 0, 0, 0);                                 \
    acc01 = MFMA_(a0, bv1, acc01, 0, 0, 0);                                 \
    acc10 = MFMA_(a1, bv0, acc10, 0, 0, 0);                                 \
    acc11 = MFMA_(a1, bv1, acc11, 0, 0, 0);                                 \
    acc20 = MFMA_(a2, bv0, acc20, 0, 0, 0);                                 \
    acc21 = MFMA_(a2, bv1, acc21, 0, 0, 0);                                 \
    acc30 = MFMA_(a3, bv0, acc30, 0, 0, 0);                                 \
    acc31 = MFMA_(a3, bv1, acc31, 0, 0, 0);                                 \
    __builtin_amdgcn_s_setprio(0); }

// one half: phase ksl=0 (stage rr=0), phase ksl=1 (stage rr=1), vmcnt, bar
#define HALF8(CB, SB, HH, DOSTG, VW)                                        \
  { PHASE8(CB, SB, HH, 0, DOSTG, 0); BAR_;                                  \
    PHASE8(CB, SB, HH, 1, DOSTG, 1);                                        \
    if ((VW) == 8) { WV8_; } else if ((VW) == 4) { WV4_; }                  \
    else if ((VW) == 0) { WV0_; }                                           \
    if ((VW) >= 0) BAR_; }

__global__ __launch_bounds__(512, 1) void gemm8b(
    const u16* __restrict__ Afrag, const u16* __restrict__ Bfrag,
    const float* __restrict__ bias, u16* __restrict__ qkh,
    u16* __restrict__ vf)
{
    __shared__ u16 lds[4][16384];   // 4 half-buffers x 32KB (A 16KB | B 16KB)
    const int tid  = threadIdx.x;
    const int lane = tid & 63;
    const int w    = tid >> 6;      // 0..7
    const int wm   = w >> 2;        // 0..1
    const int wn   = w & 3;         // 0..3
    const int la8  = lane * 8;

    // bijective XCD swizzle (384 % 8 == 0)
    const int nb  = gridDim.x * gridDim.y;
    int bid = blockIdx.y * gridDim.x + blockIdx.x;
    bid = (bid & 7) * (nb >> 3) + (bid >> 3);
    const int bx = bid % gridDim.x;     // 0..11 (N/256)
    const int by = bid / gridDim.x;     // 0..31 (M/256)

    // staging assignment: waves 0-3 -> A rows {2w, 2w+1}; 4-7 -> B rows
    const int we = w & 3;
    const u16* gmat = (w < 4) ? Afrag : Bfrag;
    const int rbase = (w < 4) ? (by * 8 + 2 * we) : (bx * 8 + 2 * we);
    const int matoff = (w < 4) ? 0 : 8192;
    const u16* gw0 = gmat + (size_t)(rbase    ) * 64 * 512 + la8;
    const u16* gw1 = gmat + (size_t)(rbase + 1) * 64 * 512 + la8;
    const int ldst00 = matoff + ((2 * we    ) * 2 + 0) * 512;
    const int ldst01 = matoff + ((2 * we    ) * 2 + 1) * 512;
    const int ldst10 = matoff + ((2 * we + 1) * 2 + 0) * 512;
    const int ldst11 = matoff + ((2 * we + 1) * 2 + 1) * 512;

    u16* hb0 = &lds[0][0];
    u16* hb1 = &lds[1][0];
    u16* hb2 = &lds[2][0];
    u16* hb3 = &lds[3][0];

    // pipeline prologue: stage halves 0,1,2 (12 loads/thread, in order);
    // vmcnt(8) certifies half 0 (halves 1,2 = 8 loads stay in flight)
#pragma unroll
    for (int h = 0; h < 3; ++h) {
        u16* sb = (h == 0) ? hb0 : (h == 1) ? hb1 : hb2;
        gload16(gw0 + (size_t)(h * 2    ) * 512, sb + ldst00);
        gload16(gw0 + (size_t)(h * 2 + 1) * 512, sb + ldst01);
        gload16(gw1 + (size_t)(h * 2    ) * 512, sb + ldst10);
        gload16(gw1 + (size_t)(h * 2 + 1) * 512, sb + ldst11);
    }
    WV8_; BAR_;

    f32x16 acc00, acc01, acc10, acc11, acc20, acc21, acc30, acc31;
#pragma unroll
    for (int r = 0; r < 16; ++r) {
        acc00[r] = 0.f; acc01[r] = 0.f; acc10[r] = 0.f; acc11[r] = 0.f;
        acc20[r] = 0.f; acc21[r] = 0.f; acc30[r] = 0.f; acc31[r] = 0.f;
    }

    // 32 halves; H in buf[H&3]; stage H+3 into buf[(H+3)&3]
#pragma unroll 1
    for (int u = 0; u < 7; ++u) {
        const int H = 4 * u;
        HALF8(hb0, hb3, H    , 1, 8);
        HALF8(hb1, hb0, H + 1, 1, 8);
        HALF8(hb2, hb1, H + 2, 1, 8);
        HALF8(hb3, hb2, H + 3, 1, 8);
    }
    HALF8(hb0, hb3, 28, 1, 8);   // stages half 31
    HALF8(hb1, hb0, 29, 0, 4);
    HALF8(hb2, hb1, 30, 0, 0);
    HALF8(hb3, hb2, 31, 0, -1);

    // epilogue: bx<8 -> Q/K row-major; bx>=8 -> V-frag direct (r9-verified)
    // C/D: col = lane&31, row = (reg&3)+8*(reg>>2)+4*(lane>>5)  [m74/m101]
    const int m0 = by * 256 + wm * 128;
    const int n0 = bx * 256 + wn * 64;
    const int hi = lane >> 5;
    f32x16 accs[4][2] = {{acc00, acc01}, {acc10, acc11}, {acc20, acc21}, {acc30, acc31}};
    if (bx < 8) {           // ---- Q/K: row-major [M][2048] ----
#pragma unroll
        for (int i = 0; i < 4; ++i) {
#pragma unroll
            for (int j = 0; j < 2; ++j) {
                const int col = n0 + j * 32 + (lane & 31);
                const float bv = bias[col];
#pragma unroll
                for (int reg = 0; reg < 16; ++reg) {
                    const int row = m0 + i * 32 + (reg & 3) + 8 * (reg >> 2) + 4 * hi;
                    _Float16 h = (_Float16)(accs[i][j][reg] + bv);
                    qkh[(size_t)row * QK_STRIDE + col] = __builtin_bit_cast(unsigned short, h);
                }
            }
        }
    } else {                // ---- V: V-frag direct, coalesced 8B stores ----
#pragma unroll
        for (int i = 0; i < 4; ++i) {
#pragma unroll
            for (int j = 0; j < 2; ++j) {
                const int col = n0 + j * 32 + (lane & 31);       // 2048..3071
                const int ch  = col - 2048;
                const float bv = bias[col];
#pragma unroll
                for (int rg = 0; rg < 4; ++rg) {
                    ushort4 wv;
                    _Float16 h0 = (_Float16)(accs[i][j][4*rg    ] + bv);
                    _Float16 h1 = (_Float16)(accs[i][j][4*rg + 1] + bv);
                    _Float16 h2 = (_Float16)(accs[i][j][4*rg + 2] + bv);
                    _Float16 h3 = (_Float16)(accs[i][j][4*rg + 3] + bv);
                    wv.x = __builtin_bit_cast(unsigned short, h0);
                    wv.y = __builtin_bit_cast(unsigned short, h1);
                    wv.z = __builtin_bit_cast(unsigned short, h2);
                    wv.w = __builtin_bit_cast(unsigned short, h3);
                    const size_t chunk = (size_t)((m0 + i * 32 + 8 * rg) >> 4) * 32 + (ch >> 5);
                    const int interior = ((ch & 31) + 32 * (rg & 1)) * 8 + 4 * hi;
                    *(ushort4*)(vf + chunk * 512 + interior) = wv;
                }
            }
        }
    }
}

// ---------------- gemm_s (proven): Wo, BM=128 x BN=128, 512 blocks --------
#define STAGE_S0(NB, KO) { gload16(gA0 + (KO), (NB) + lsA0); gload16(gB0 + (KO), (NB) + lsB0); }
#define STAGE_S1(NB, KO) { gload16(gA1 + (KO), (NB) + lsA1); gload16(gB1 + (KO), (NB) + lsB1); }

#define TILE_S(CB, NB, KT, DOSTG, VW)                                      \
  {                                                                        \
    const size_t ko = (size_t)((KT) + 2) * 1024;                           \
    half8 a0 = *(const half8*)((CB) + oA);                                 \
    half8 a1 = *(const half8*)((CB) + oA + 1024);                          \
    half8 b0v = *(const half8*)((CB) + oB);                                \
    half8 b1v = *(const half8*)((CB) + oB + 1024);                         \
    if (DOSTG) STAGE_S0(NB, ko);                                           \
    __builtin_amdgcn_s_setprio(1);                                         \
    acc00 = MFMA_(a0, b0v, acc00, 0, 0, 0);                                \
    acc01 = MFMA_(a0, b1v, acc01, 0, 0, 0);                                \
    acc10 = MFMA_(a1, b0v, acc10, 0, 0, 0);                                \
    acc11 = MFMA_(a1, b1v, acc11, 0, 0, 0);                                \
    __builtin_amdgcn_s_setprio(0);                                         \
    a0 = *(const half8*)((CB) + oA + 512);                                 \
    a1 = *(const half8*)((CB) + oA + 1536);                                \
    b0v = *(const half8*)((CB) + oB + 512);                                \
    b1v = *(const half8*)((CB) + oB + 1536);                               \
    if (DOSTG) STAGE_S1(NB, ko);                                           \
    __builtin_amdgcn_s_setprio(1);                                         \
    acc00 = MFMA_(a0, b0v, acc00, 0, 0, 0);                                \
    acc01 = MFMA_(a0, b1v, acc01, 0, 0, 0);                                \
    acc10 = MFMA_(a1, b0v, acc10, 0, 0, 0);                                \
    acc11 = MFMA_(a1, b1v, acc11, 0, 0, 0);                                \
    __builtin_amdgcn_s_setprio(0);                                         \
    if ((VW) == 4)      asm volatile("s_waitcnt vmcnt(4) lgkmcnt(0)" ::: "memory"); \
    else if ((VW) == 0) asm volatile("s_waitcnt vmcnt(0) lgkmcnt(0)" ::: "memory"); \
    else                asm volatile("s_waitcnt lgkmcnt(0)" ::: "memory"); \
    asm volatile("s_barrier" ::: "memory");                                \
  }

__global__ __launch_bounds__(256, 2) void gemm_s(
    const u16* __restrict__ Afrag, const u16* __restrict__ Bfrag,
    const float* __restrict__ bias, float* __restrict__ Cout, int Ndim)
{
    __shared__ u16 lds[3][8192];
    const int tid  = threadIdx.x;
    const int lane = tid & 63;
    const int wave = tid >> 6;
    const int wm   = wave >> 1;
    const int wn   = wave & 1;
    const int la8  = lane * 8;

    const int nb  = gridDim.x * gridDim.y;
    int bid = blockIdx.y * gridDim.x + blockIdx.x;
    bid = (bid & 7) * (nb >> 3) + (bid >> 3);
    const int bx = bid % gridDim.x;
    const int by = bid / gridDim.x;

    const u16* gA0 = Afrag + ((size_t)(by*4 + ((wave    )>>1))*64 + ((wave    )&1))*512 + la8;
    const u16* gA1 = Afrag + ((size_t)(by*4 + ((wave+ 4 )>>1))*64 + ((wave+ 4 )&1))*512 + la8;
    const u16* gB0 = Bfrag + ((size_t)(bx*4 + ((wave    )>>1))*64 + ((wave    )&1))*512 + la8;
    const u16* gB1 = Bfrag + ((size_t)(bx*4 + ((wave+ 4 )>>1))*64 + ((wave+ 4 )&1))*512 + la8;
    const int lsA0 = (wave    ) * 512;
    const int lsA1 = (wave + 4) * 512;
    const int lsB0 = 4096 + (wave    ) * 512;
    const int lsB1 = 4096 + (wave + 4) * 512;

    const int oA = wm * 2048 + la8;
    const int oB = 4096 + wn * 2048 + la8;

    u16* b0 = &lds[0][0];
    u16* b1 = &lds[1][0];
    u16* b2 = &lds[2][0];

    STAGE_S0(b0, 0); STAGE_S1(b0, 0);
    STAGE_S0(b1, 1024); STAGE_S1(b1, 1024);
    asm volatile("s_waitcnt vmcnt(4)" ::: "memory");
    asm volatile("s_barrier" ::: "memory");

    f32x16 acc00, acc01, acc10, acc11;
#pragma unroll
    for (int r = 0; r < 16; ++r) { acc00[r] = 0.f; acc01[r] = 0.f; acc10[r] = 0.f; acc11[r] = 0.f; }

#pragma unroll 1
    for (int kt = 0; kt < NT - 2; kt += 3) {
        TILE_S(b0, b2, kt,     1, 4);
        TILE_S(b1, b0, kt + 1, 1, 4);
        TILE_S(b2, b1, kt + 2, 1, 4);
    }
    TILE_S(b0, b2, NT - 2, 0, 0);
    TILE_S(b1, b2, NT - 1, 0, -1);

    const int m0 = by * 128 + wm * 64;
    const int n0 = bx * 128 + wn * 64;
    f32x16 accs[2][2] = {{acc00, acc01}, {acc10, acc11}};
#pragma unroll
    for (int i = 0; i < 2; ++i) {
#pragma unroll
        for (int j = 0; j < 2; ++j) {
            const int col = n0 + j * 32 + (lane & 31);
            const float bv = bias[col];
#pragma unroll
            for (int reg = 0; reg < 16; ++reg) {
                const int row = m0 + i * 32 + (reg & 3) + 8 * (reg >> 2) + 4 * (lane >> 5);
                Cout[(size_t)row * Ndim + col] = accs[i][j][reg] + bv;
            }
        }
    }
}

// ---------------- attn_rm (r8/r9-verified): MFMA windowed attention -------
__global__ __launch_bounds__(64) void attn_rm(
    const u16* __restrict__ qkh, const u16* __restrict__ vf,
    u16* __restrict__ ctxf)
{
    const int l   = threadIdx.x;
    const int q   = l & 31;
    const int hi  = l >> 5;
    const int t0  = blockIdx.x * 32;
    const int t0l = t0 & (T_ - 1);

    const int r1 = min(max(t0 - 16 + q, 0), M_ - 1);
    const int r2 = min(max(t0 + 16 + q, 0), M_ - 1);
    const u16* a1p = qkh + (size_t)r1 * QK_STRIDE + 1024 + hi * 8;
    const u16* a2p = qkh + (size_t)r2 * QK_STRIDE + 1024 + hi * 8;
    const u16* qp  = qkh + (size_t)(t0 + q) * QK_STRIDE + hi * 8;

    f32x16 sc1, sc2;
#pragma unroll
    for (int r = 0; r < 16; ++r) { sc1[r] = 0.f; sc2[r] = 0.f; }
#pragma unroll 8
    for (int ks = 0; ks < 64; ++ks) {
        half8 a1 = LD8_(a1p + ks * 16);
        half8 a2 = LD8_(a2p + ks * 16);
        half8 qb = LD8_(qp  + ks * 16);
        sc1 = MFMA_(a1, qb, sc1, 0, 0, 0);
        sc2 = MFMA_(a2, qb, sc2, 0, 0, 0);
    }

    float px1[16], px2[16];
#pragma unroll
    for (int r = 0; r < 16; ++r) {
        px1[r] = __shfl_xor(sc1[r], 32);
        px2[r] = __shfl_xor(sc2[r], 32);
    }

    const int plo = max(q + 8, 16 - t0l);
    const int phi = min(q + 24, (T_ + 15) - t0l);
    float s[64];
#pragma unroll
    for (int p = 0; p < 64; ++p) {
        const int row = p & 31;
        const int h   = (row >> 2) & 1;
        const int rg  = (row & 3) + 4 * (row >> 3);
        const float own = (p < 32) ? sc1[rg] : sc2[rg];
        const float oth = (p < 32) ? px1[rg] : px2[rg];
        const float v = (h == hi) ? own : oth;
        s[p] = (p >= plo && p <= phi) ? v * 0.03125f : -3.0e38f;
    }

    float mx = s[0];
#pragma unroll
    for (int p = 1; p < 64; ++p) mx = fmaxf(mx, s[p]);
    float den = 0.f;
#pragma unroll
    for (int p = 0; p < 64; ++p) { const float w = __expf(s[p] - mx); s[p] = w; den += w; }
    const float inv = 1.f / den;

    half8 pa0, pa1, pa2, pa3;
#pragma unroll
    for (int e = 0; e < 8; ++e) {
        pa0[e] = (_Float16)((hi ? s[ 8 + e] : s[ 0 + e]) * inv);
        pa1[e] = (_Float16)((hi ? s[24 + e] : s[16 + e]) * inv);
        pa2[e] = (_Float16)((hi ? s[40 + e] : s[32 + e]) * inv);
        pa3[e] = (_Float16)((hi ? s[56 + e] : s[48 + e]) * inv);
    }

    const int s0i = (t0 - 16) >> 4;
    const u16* vb0p = vf + (size_t)min(max(s0i    , 0), M_/16 - 1) * 16384 + l * 8;
    const u16* vb1p = vf + (size_t)min(max(s0i + 1, 0), M_/16 - 1) * 16384 + l * 8;
    const u16* vb2p = vf + (size_t)min(max(s0i + 2, 0), M_/16 - 1) * 16384 + l * 8;
    const u16* vb3p = vf + (size_t)min(max(s0i + 3, 0), M_/16 - 1) * 16384 + l * 8;
    const size_t ctxb = (size_t)(t0 >> 5) * 32768;
    const int lpo = 32 * ((l >> 3) & 1);
    const int e7  = l & 7;
#pragma unroll 2
    for (int n = 0; n < 32; ++n) {
        half8 v0 = LD8_(vb0p + n * 512);
        half8 v1 = LD8_(vb1p + n * 512);
        half8 v2 = LD8_(vb2p + n * 512);
        half8 v3 = LD8_(vb3p + n * 512);
        f32x16 o;
#pragma unroll
        for (int r = 0; r < 16; ++r) o[r] = 0.f;
        o = MFMA_(pa0, v0, o, 0, 0, 0);
        o = MFMA_(pa1, v1, o, 0, 0, 0);
        o = MFMA_(pa2, v2, o, 0, 0, 0);
        o = MFMA_(pa3, v3, o, 0, 0, 0);
        u16* cp = ctxf + ctxb + (size_t)(2 * n + (q >> 4)) * 512 + e7;
#pragma unroll
        for (int r = 0; r < 16; ++r) {
            const int mrow = (r & 3) + 8 * (r >> 2) + 4 * hi;
            _Float16 hv = (_Float16)o[r];
            cp[(mrow + lpo) * 8] = __builtin_bit_cast(unsigned short, hv);
        }
    }
}

// ---------------- host launch ----------------
extern "C" void kernel_launch(void* const* d_in, const int* in_sizes, int n_in,
                              void* d_out, int out_size, void* d_ws, size_t ws_size,
                              hipStream_t stream) {
    const float* x  = (const float*)d_in[0];
    const float* Wq = (const float*)d_in[1];
    const float* bq = (const float*)d_in[2];
    const float* Wk = (const float*)d_in[3];
    const float* bk = (const float*)d_in[4];
    const float* Wv = (const float*)d_in[5];
    const float* bv = (const float*)d_in[6];
    const float* Wo = (const float*)d_in[7];
    const float* bo = (const float*)d_in[8];
    float* out = (float*)d_out;

    const size_t MC = (size_t)M_ * C_;              // 8M u16
    u16* xf   = (u16*)d_ws;                         // 8M  (x frag)
    u16* wfq  = xf   + MC;                          // 3M  (Wq;Wk;Wv frag)
    u16* wfo  = wfq  + 3 * (size_t)C_ * C_;         // 1M  (Wo frag)
    u16* qkh  = wfo  + (size_t)C_ * C_;             // 16M (row-major Q|K)
    u16* vf   = qkh  + (size_t)M_ * QK_STRIDE;      // 8M  (V-frag)
    u16* ctxf = vf   + MC;                          // 8M  (frag-major)
    float* bcat = (float*)(ctxf + MC);              // 3072 floats

    prologue2<<<3084, 256, 0, stream>>>(x, Wq, Wk, Wv, Wo, bq, bk, bv,
                                        xf, wfq, wfo, bcat);

    dim3 gqkv(3072 / 256, M_ / 256);   // (12, 32) = 384 blocks, 1/CU (8 waves)
    gemm8b<<<gqkv, 512, 0, stream>>>(xf, wfq, bcat, qkh, vf);

    attn_rm<<<M_ / 32, 64, 0, stream>>>(qkh, vf, ctxf);

    dim3 go(C_ / 128, M_ / 128);       // (8, 64) = 512 blocks, 2/CU
    gemm_s<<<go, 256, 0, stream>>>(ctxf, wfo, bo, out, C_);
}